// Round 2
// baseline (640.767 us; speedup 1.0000x reference)
//
#include <hip/hip_runtime.h>
#include <hip/hip_cooperative_groups.h>
#include <math.h>

namespace cg = cooperative_groups;

namespace {

constexpr int B_ = 256;
constexpr int R_ = 1152;
constexpr int C_ = 10;
constexpr int O_ = 16;
constexpr int I_ = 8;
constexpr int CO_ = C_ * O_;          // 160
constexpr int WRI_ = C_ * O_ * I_;    // 1280 floats of W per route

constexpr int KS2_ = 72;              // r-splits in s-phase
constexpr int RC2_ = R_ / KS2_;       // 16 routes per s-block
constexpr int BH_  = 128;             // batch-half per s-block
constexpr int RT_  = 3;               // routes per a-block (384 balanced blocks)

constexpr int GRID_  = 480;           // cooperative grid: 2 blocks/CU guaranteed
constexpr int NVB_T_ = 1152;          // transpose tiles
constexpr int NVB_S_ = 1440;          // (c=10, ks=72, bh=2); 1440/480 = 3 even rounds
constexpr int NVB_V_ = 640;           // 160 co x 4 bseg
constexpr int NVB_A_ = R_ / RT_;      // 384

// fallback tier-3 params
constexpr int KSF_ = 16;
constexpr int RCF_ = R_ / KSF_;       // 72
constexpr int MBF_ = 16;

// ws layout (float offsets)
constexpr size_t XT_OFF    = 0;                          // [R][B][I]
constexpr size_t XT_N      = (size_t)R_ * B_ * I_;       // 2,359,296
constexpr size_t SP_OFF    = XT_OFF + XT_N;              // [CO][KS2][B]
constexpr size_t SP_N      = (size_t)CO_ * KS2_ * B_;    // 2,949,120
constexpr size_t V_OFF     = SP_OFF + SP_N;              // [B][CO]
constexpr size_t V_N       = (size_t)B_ * CO_;           // 40,960
constexpr size_t BIJ_OFF   = V_OFF + V_N;                // [C][R]
constexpr size_t BIJ_N     = (size_t)C_ * R_;            // 11,520
constexpr size_t FL_TOTAL  = BIJ_OFF + BIJ_N;

__device__ __forceinline__ float squashf(float s) {
    // faithful to reference: s^2*s/((1+s^2)*sqrt(s^2)) == s*|s|/(1+s^2)
    return s * fabsf(s) / (1.0f + s * s);
}

// ---------------------------------------------------------------------------
// shared-memory blocks per phase (union'd in the fused kernel)
// ---------------------------------------------------------------------------
struct TrSh { float t[8][32][8]; };                              // 8 KB
struct S5Sh {                                                    // ~72.1 KB
    float4 xl[RC2_ * 256];      // 64 KB, swizzled x chunk
    float  wl[RC2_ * 128];      // 8 KB, cw-scaled W chunk
    float  cwch[RC2_];
    float  sred[8];
};
struct V3Sh { float sh[192]; };                                  // 768 B
struct A4Sh {                                                    // ~27.4 KB
    float xrow[RT_ * B_ * I_];  // 24 KB
    float part[RT_][240];
};
union ShAll { TrSh tr; S5Sh s5; V3Sh v3; A4Sh a4; };

// ===========================================================================
// tr_body: x[b,r,i] -> xT[r,b,i] (+ zero bijT).  tile 8 b x 32 r.  vb<1152.
// ===========================================================================
__device__ __forceinline__ void tr_body(int vb, TrSh& sh,
                                        const float* __restrict__ x,
                                        float* __restrict__ xT,
                                        float* __restrict__ bijT) {
    const int tid = threadIdx.x;
    __syncthreads();                       // LDS reuse guard across vb rounds
    {
        const int gi = vb * 256 + tid;
        if (gi < C_ * R_) bijT[gi] = 0.f;
    }
    const int r0 = (vb % 36) * 32;
    const int b0 = (vb / 36) * 8;
    {
        const int rl = tid & 31, bl = tid >> 5;
        const float4* p = (const float4*)(x + ((size_t)(b0 + bl) * R_ + (r0 + rl)) * I_);
        const float4 a0 = p[0], a1 = p[1];
        float* d = &sh.t[bl][rl][0];
        *(float4*)d = a0;
        *(float4*)(d + 4) = a1;
    }
    __syncthreads();
    {
        const int f = tid & 7, rw = tid >> 3;   // f = b-local
        const float* s8 = &sh.t[f][rw][0];
        const float4 a0 = *(const float4*)s8, a1 = *(const float4*)(s8 + 4);
        float* d = xT + ((size_t)(r0 + rw) * B_ + (b0 + f)) * I_;
        *(float4*)d = a0;
        *(float4*)(d + 4) = a1;
    }
}

// ===========================================================================
// s5_body: spart[c*O+o, ks, b] = sum_{r in chunk} cw[r,c]*dot(W[r,c,o,:],xT[r,b,:])
// vb = (ks*2+bh)*10 + c.  256 thr = 4 o-waves over 128 b's (acc[4][2]).
// x chunk (16r x 128b x 8i = 64KB) staged in LDS, XOR-swizzled on f4 index;
// cw folded into the staged W -> inner loop pure fma.
// ===========================================================================
__device__ __forceinline__ void s5_body(int vb, int uni, S5Sh& sh,
                                        const float* __restrict__ xT,
                                        const float* __restrict__ Wm,
                                        const float* __restrict__ bijT,
                                        float* __restrict__ spart) {
    const int tid  = threadIdx.x;
    const int lane = tid & 63;
    const int c    = vb % 10;
    const int bh   = (vb / 10) & 1;
    const int ks   = vb / 20;
    const int r0   = ks * RC2_;

    // ---- softmax over routes for capsule c -> cwch[0..15] ----
    if (!uni) {
        const float* bc = bijT + (size_t)c * R_;
        float bv[5];
        #pragma unroll
        for (int k = 0; k < 5; ++k) {
            const int r = tid + 256 * k;
            bv[k] = (r < R_) ? bc[r] : -1e30f;
        }
        float m = -1e30f;
        #pragma unroll
        for (int k = 0; k < 5; ++k) m = fmaxf(m, bv[k]);
        #pragma unroll
        for (int off = 32; off > 0; off >>= 1)
            m = fmaxf(m, __shfl_down(m, off, 64));
        if (lane == 0) sh.sred[tid >> 6] = m;
        __syncthreads();
        const float bm = fmaxf(fmaxf(sh.sred[0], sh.sred[1]),
                               fmaxf(sh.sred[2], sh.sred[3]));
        float se = 0.f;
        #pragma unroll
        for (int k = 0; k < 5; ++k)
            se += (bv[k] > -1e29f) ? expf(bv[k] - bm) : 0.f;
        #pragma unroll
        for (int off = 32; off > 0; off >>= 1)
            se += __shfl_down(se, off, 64);
        if (lane == 0) sh.sred[4 + (tid >> 6)] = se;
        __syncthreads();
        const float inv = 1.0f / (sh.sred[4] + sh.sred[5] + sh.sred[6] + sh.sred[7]);
        if (tid < RC2_) sh.cwch[tid] = expf(bc[r0 + tid] - bm) * inv;
    }
    __syncthreads();

    // ---- stage cw-scaled W chunk ----
    {
        const float4* src = (const float4*)(Wm + ((size_t)r0 * C_ + c) * 128);
        float4* dst = (float4*)sh.wl;
        #pragma unroll
        for (int k = 0; k < (RC2_ * 32) / 256; ++k) {      // 2 iters
            const int idx = tid + 256 * k;                 // 0..511
            const int r = idx >> 5, q = idx & 31;
            float4 wv = src[(size_t)r * (C_ * 32) + q];
            const float cw = uni ? (1.0f / (float)R_) : sh.cwch[r];
            wv.x *= cw; wv.y *= cw; wv.z *= cw; wv.w *= cw;
            dst[idx] = wv;
        }
    }
    // ---- stage x chunk (swizzled) ----
    {
        const float4* src = (const float4*)(xT + ((size_t)r0 * B_ + bh * BH_) * I_);
        #pragma unroll
        for (int k = 0; k < (RC2_ * 256) / 256; ++k) {     // 16 iters
            const int idx = tid + 256 * k;                 // 0..4095
            const int r = idx >> 8, er = idx & 255;
            sh.xl[r * 256 + (er ^ ((er >> 3) & 7))] = src[(size_t)r * 512 + er];
        }
    }
    __syncthreads();

    const int o0 = (tid >> 6) * 4;        // wave-uniform; LDS W reads broadcast
    const int e00 = (2 * lane) ^ ((lane >> 2) & 7);
    const int e01 = e00 ^ 1;

    float acc[4][2];
    #pragma unroll
    for (int oo = 0; oo < 4; ++oo)
        #pragma unroll
        for (int bb = 0; bb < 2; ++bb) acc[oo][bb] = 0.f;

    #pragma unroll 4
    for (int r = 0; r < RC2_; ++r) {
        const int ra = r * 256;
        const float4 a00 = sh.xl[ra + e00];
        const float4 a01 = sh.xl[ra + e01];
        const float4 a10 = sh.xl[ra + 128 + e00];
        const float4 a11 = sh.xl[ra + 128 + e01];
        float xr[2][8];
        xr[0][0] = a00.x; xr[0][1] = a00.y; xr[0][2] = a00.z; xr[0][3] = a00.w;
        xr[0][4] = a01.x; xr[0][5] = a01.y; xr[0][6] = a01.z; xr[0][7] = a01.w;
        xr[1][0] = a10.x; xr[1][1] = a10.y; xr[1][2] = a10.z; xr[1][3] = a10.w;
        xr[1][4] = a11.x; xr[1][5] = a11.y; xr[1][6] = a11.z; xr[1][7] = a11.w;

        const float4* wp = (const float4*)&sh.wl[r * 128 + o0 * 8];
        #pragma unroll
        for (int oo = 0; oo < 4; ++oo) {
            const float4 w0 = wp[oo * 2 + 0];
            const float4 w1 = wp[oo * 2 + 1];
            #pragma unroll
            for (int bb = 0; bb < 2; ++bb) {
                float a = acc[oo][bb];
                a = fmaf(xr[bb][0], w0.x, a);
                a = fmaf(xr[bb][1], w0.y, a);
                a = fmaf(xr[bb][2], w0.z, a);
                a = fmaf(xr[bb][3], w0.w, a);
                a = fmaf(xr[bb][4], w1.x, a);
                a = fmaf(xr[bb][5], w1.y, a);
                a = fmaf(xr[bb][6], w1.z, a);
                a = fmaf(xr[bb][7], w1.w, a);
                acc[oo][bb] = a;
            }
        }
    }

    float* sp = spart + (((size_t)(c * O_ + o0)) * KS2_ + ks) * B_ + bh * BH_ + lane;
    #pragma unroll
    for (int oo = 0; oo < 4; ++oo)
        #pragma unroll
        for (int bb = 0; bb < 2; ++bb)
            sp[(size_t)oo * KS2_ * B_ + bb * 64] = acc[oo][bb];
}

// ===========================================================================
// v3_body: dest[b,co] = squash(sum_ks spart[co,ks,b]).  vb < 640.
// ===========================================================================
__device__ __forceinline__ void v3_body(int vb, V3Sh& sh,
                                        const float* __restrict__ spart,
                                        float* __restrict__ dest) {
    const int tid  = threadIdx.x;
    const int lane = tid & 63;
    const int g    = tid >> 6;
    const int co2  = vb % CO_;
    const int bseg = vb / CO_;
    __syncthreads();                       // LDS reuse guard
    const float* p = spart + (((size_t)co2) * KS2_ + g * 18) * B_ + bseg * 64 + lane;
    float t0 = 0.f, t1 = 0.f;
    #pragma unroll
    for (int j = 0; j < 18; j += 2) {
        t0 += p[(size_t)(j + 0) * B_];
        t1 += p[(size_t)(j + 1) * B_];
    }
    const float s = t0 + t1;
    if (g) sh.sh[(g - 1) * 64 + lane] = s;
    __syncthreads();
    if (g == 0) {
        const float tot = s + sh.sh[lane] + sh.sh[64 + lane] + sh.sh[128 + lane];
        const int b = bseg * 64 + lane;
        dest[(size_t)b * CO_ + co2] = squashf(tot);
    }
}

// ===========================================================================
// a4_body: bijT[c, r0+rr] += (1/B) sum_o sum_i W[r,c,o,i]*(sum_b v[b,c,o]*x[r,b,i])
// vb < 384 (RT_=3 routes per block).  256 thr: cp = co-pair (80), bg = b-third.
// Factorized: acc_i[r][co][i] = sum_b v[b,co]*x[r,b,i], then one W-dot.
// ===========================================================================
__device__ __forceinline__ void a4_body(int vb, A4Sh& sh,
                                        const float* __restrict__ xT,
                                        const float* __restrict__ Wm,
                                        const float* __restrict__ vglob,
                                        float* __restrict__ bijT) {
    const int tid = threadIdx.x;
    const int r0  = vb * RT_;
    __syncthreads();                       // LDS reuse guard
    {
        const float4* src = (const float4*)(xT + (size_t)r0 * B_ * I_);
        float4* dst = (float4*)sh.xrow;
        #pragma unroll
        for (int k = 0; k < (RT_ * B_ * I_) / 4 / 256; ++k)   // 6 iters
            dst[tid + 256 * k] = src[tid + 256 * k];
    }
    __syncthreads();

    const int cp = tid % 80;          // co-pair: co = {2cp, 2cp+1}
    const int bg = tid / 80;          // 0..2 active, 3 idle (16 threads)

    float acc[RT_][2][8];
    #pragma unroll
    for (int rr = 0; rr < RT_; ++rr)
        #pragma unroll
        for (int j = 0; j < 2; ++j)
            #pragma unroll
            for (int i = 0; i < 8; ++i) acc[rr][j][i] = 0.f;
    float pr[RT_];
    #pragma unroll
    for (int rr = 0; rr < RT_; ++rr) pr[rr] = 0.f;

    if (bg < 3) {
        const int bA = bg * 86;
        const int bB = (bg == 2) ? 256 : (bA + 86);
        const float* vp = vglob + 2 * cp;
        #pragma unroll 2
        for (int b = bA; b < bB; ++b) {
            const float2 vv = *(const float2*)(vp + (size_t)b * CO_);
            #pragma unroll
            for (int rr = 0; rr < RT_; ++rr) {
                const float* xr = &sh.xrow[(rr * B_ + b) * I_];
                const float4 y0 = *(const float4*)xr;
                const float4 y1 = *(const float4*)(xr + 4);
                acc[rr][0][0] = fmaf(vv.x, y0.x, acc[rr][0][0]);
                acc[rr][0][1] = fmaf(vv.x, y0.y, acc[rr][0][1]);
                acc[rr][0][2] = fmaf(vv.x, y0.z, acc[rr][0][2]);
                acc[rr][0][3] = fmaf(vv.x, y0.w, acc[rr][0][3]);
                acc[rr][0][4] = fmaf(vv.x, y1.x, acc[rr][0][4]);
                acc[rr][0][5] = fmaf(vv.x, y1.y, acc[rr][0][5]);
                acc[rr][0][6] = fmaf(vv.x, y1.z, acc[rr][0][6]);
                acc[rr][0][7] = fmaf(vv.x, y1.w, acc[rr][0][7]);
                acc[rr][1][0] = fmaf(vv.y, y0.x, acc[rr][1][0]);
                acc[rr][1][1] = fmaf(vv.y, y0.y, acc[rr][1][1]);
                acc[rr][1][2] = fmaf(vv.y, y0.z, acc[rr][1][2]);
                acc[rr][1][3] = fmaf(vv.y, y0.w, acc[rr][1][3]);
                acc[rr][1][4] = fmaf(vv.y, y1.x, acc[rr][1][4]);
                acc[rr][1][5] = fmaf(vv.y, y1.y, acc[rr][1][5]);
                acc[rr][1][6] = fmaf(vv.y, y1.z, acc[rr][1][6]);
                acc[rr][1][7] = fmaf(vv.y, y1.w, acc[rr][1][7]);
            }
        }
        #pragma unroll
        for (int rr = 0; rr < RT_; ++rr) {
            const float* wp = Wm + (((size_t)(r0 + rr)) * CO_ + 2 * cp) * I_;
            const float4 wa0 = *(const float4*)wp;
            const float4 wa1 = *(const float4*)(wp + 4);
            const float4 wb0 = *(const float4*)(wp + 8);
            const float4 wb1 = *(const float4*)(wp + 12);
            float p0 = acc[rr][0][0] * wa0.x;
            p0 = fmaf(acc[rr][0][1], wa0.y, p0);
            p0 = fmaf(acc[rr][0][2], wa0.z, p0);
            p0 = fmaf(acc[rr][0][3], wa0.w, p0);
            p0 = fmaf(acc[rr][0][4], wa1.x, p0);
            p0 = fmaf(acc[rr][0][5], wa1.y, p0);
            p0 = fmaf(acc[rr][0][6], wa1.z, p0);
            p0 = fmaf(acc[rr][0][7], wa1.w, p0);
            float p1 = acc[rr][1][0] * wb0.x;
            p1 = fmaf(acc[rr][1][1], wb0.y, p1);
            p1 = fmaf(acc[rr][1][2], wb0.z, p1);
            p1 = fmaf(acc[rr][1][3], wb0.w, p1);
            p1 = fmaf(acc[rr][1][4], wb1.x, p1);
            p1 = fmaf(acc[rr][1][5], wb1.y, p1);
            p1 = fmaf(acc[rr][1][6], wb1.z, p1);
            p1 = fmaf(acc[rr][1][7], wb1.w, p1);
            pr[rr] = p0 + p1;
        }
    }
    if (bg < 3) {
        #pragma unroll
        for (int rr = 0; rr < RT_; ++rr) sh.part[rr][tid] = pr[rr];
    }
    __syncthreads();
    if (tid < RT_ * 10) {
        const int r = tid / 10, c2 = tid % 10;
        float s = 0.f;
        #pragma unroll
        for (int g2 = 0; g2 < 3; ++g2)
            #pragma unroll
            for (int op = 0; op < 8; ++op)
                s += sh.part[r][g2 * 80 + c2 * 8 + op];
        bijT[(size_t)c2 * R_ + (r0 + r)] += s * (1.0f / (float)B_);
    }
}

// ===========================================================================
// FUSED cooperative kernel: 1 launch replaces 9.
// ===========================================================================
__global__ __launch_bounds__(256, 2) void k_fused(const float* __restrict__ x,
                                                  const float* __restrict__ Wm,
                                                  float* __restrict__ out,
                                                  float* __restrict__ xT,
                                                  float* __restrict__ spart,
                                                  float* __restrict__ v,
                                                  float* __restrict__ bijT) {
    __shared__ ShAll sm;
    cg::grid_group gg = cg::this_grid();
    const int bid = blockIdx.x;

    for (int vb = bid; vb < NVB_T_; vb += GRID_) tr_body(vb, sm.tr, x, xT, bijT);
    gg.sync();

    for (int it = 0; it < 3; ++it) {
        const int uni = (it == 0) ? 1 : 0;
        for (int vb = bid; vb < NVB_S_; vb += GRID_)
            s5_body(vb, uni, sm.s5, xT, Wm, bijT, spart);
        gg.sync();
        float* dst = (it == 2) ? out : v;
        for (int vb = bid; vb < NVB_V_; vb += GRID_)
            v3_body(vb, sm.v3, spart, dst);
        if (it < 2) {
            gg.sync();
            for (int vb = bid; vb < NVB_A_; vb += GRID_)
                a4_body(vb, sm.a4, xT, Wm, v, bijT);
            gg.sync();
        }
    }
}

// ===========================================================================
// Non-cooperative fallback wrappers (same bodies, 9 launches)
// ===========================================================================
__global__ __launch_bounds__(256) void k_trw(const float* __restrict__ x,
                                             float* __restrict__ xT,
                                             float* __restrict__ bijT) {
    __shared__ TrSh sh;
    tr_body(blockIdx.x, sh, x, xT, bijT);
}
__global__ __launch_bounds__(256) void k_s5w(const float* __restrict__ xT,
                                             const float* __restrict__ Wm,
                                             const float* __restrict__ bijT,
                                             float* __restrict__ spart, int uni) {
    __shared__ S5Sh sh;
    s5_body(blockIdx.x, uni, sh, xT, Wm, bijT, spart);
}
__global__ __launch_bounds__(256) void k_v3w(const float* __restrict__ spart,
                                             float* __restrict__ dest) {
    __shared__ V3Sh sh;
    v3_body(blockIdx.x, sh, spart, dest);
}
__global__ __launch_bounds__(256) void k_a4w(const float* __restrict__ xT,
                                             const float* __restrict__ Wm,
                                             const float* __restrict__ vglob,
                                             float* __restrict__ bijT) {
    __shared__ A4Sh sh;
    a4_body(blockIdx.x, sh, xT, Wm, vglob, bijT);
}

// ===========================================================================
// FALLBACK tier 3 (tiny ws)
// ===========================================================================
template <bool UNIFORM>
__global__ __launch_bounds__(256) void k_s_f(const float* __restrict__ x,
                                             const float* __restrict__ Wm,
                                             const float* __restrict__ cij,
                                             float* __restrict__ s_out) {
    const int o  = threadIdx.x & 15;
    const int tb = threadIdx.x >> 4;
    const int b  = blockIdx.z * MBF_ + tb;
    const int c  = blockIdx.y;
    const int r0 = blockIdx.x * RCF_;

    const float* xp = x + ((size_t)b * R_ + r0) * I_;
    const float* wp = Wm + (((size_t)r0 * C_ + c) * O_ + o) * I_;
    const float* cp = cij + (size_t)r0 * C_ + c;

    float acc = 0.f;
    #pragma unroll 4
    for (int r = 0; r < RCF_; ++r) {
        const float4 xv0 = *(const float4*)(xp);
        const float4 xv1 = *(const float4*)(xp + 4);
        const float4 wv0 = *(const float4*)(wp);
        const float4 wv1 = *(const float4*)(wp + 4);
        const float p0 = fmaf(xv0.y, wv0.y, xv0.x * wv0.x);
        const float p1 = fmaf(xv0.w, wv0.w, xv0.z * wv0.z);
        const float p2 = fmaf(xv1.y, wv1.y, xv1.x * wv1.x);
        const float p3 = fmaf(xv1.w, wv1.w, xv1.z * wv1.z);
        const float cw = UNIFORM ? (1.0f / (float)R_) : cp[0];
        acc = fmaf(cw, (p0 + p1) + (p2 + p3), acc);
        xp += I_;
        wp += WRI_;
        cp += C_;
    }
    atomicAdd(&s_out[((size_t)b * C_ + c) * O_ + o], acc);
}

__global__ __launch_bounds__(256) void k_a_f(const float* __restrict__ x,
                                             const float* __restrict__ Wm,
                                             const float* __restrict__ s_in,
                                             float* __restrict__ amean) {
    __shared__ __align__(16) float wlds[2 * WRI_];
    __shared__ float red[4][2 * C_];

    const int tid = threadIdx.x;
    const int r0  = blockIdx.x * 2;

    const float* wsrc = Wm + (size_t)r0 * WRI_;
    #pragma unroll
    for (int k = 0; k < 2 * WRI_ / 256; ++k)
        wlds[tid + 256 * k] = wsrc[tid + 256 * k];
    __syncthreads();

    const int b    = tid;
    const int lane = tid & 63;
    const int wv   = tid >> 6;

    float xv[2][I_];
    const float4* xp4 = (const float4*)(x + ((size_t)b * R_ + r0) * I_);
    #pragma unroll
    for (int rr = 0; rr < 2; ++rr) {
        const float4 a0 = xp4[rr * 2 + 0];
        const float4 a1 = xp4[rr * 2 + 1];
        xv[rr][0] = a0.x; xv[rr][1] = a0.y; xv[rr][2] = a0.z; xv[rr][3] = a0.w;
        xv[rr][4] = a1.x; xv[rr][5] = a1.y; xv[rr][6] = a1.z; xv[rr][7] = a1.w;
    }

    #pragma unroll 1
    for (int c = 0; c < C_; ++c) {
        const float4* sp4 = (const float4*)(s_in + ((size_t)b * C_ + c) * O_);
        float v[O_];
        #pragma unroll
        for (int q = 0; q < 4; ++q) {
            const float4 sv = sp4[q];
            v[q * 4 + 0] = squashf(sv.x);
            v[q * 4 + 1] = squashf(sv.y);
            v[q * 4 + 2] = squashf(sv.z);
            v[q * 4 + 3] = squashf(sv.w);
        }
        #pragma unroll 1
        for (int rr = 0; rr < 2; ++rr) {
            const float4* wl4 = (const float4*)&wlds[(rr * C_ + c) * O_ * I_];
            float a = 0.f;
            #pragma unroll
            for (int o = 0; o < O_; ++o) {
                const float4 w0 = wl4[o * 2 + 0];
                const float4 w1 = wl4[o * 2 + 1];
                float u = xv[rr][0] * w0.x;
                u = fmaf(xv[rr][1], w0.y, u);
                u = fmaf(xv[rr][2], w0.z, u);
                u = fmaf(xv[rr][3], w0.w, u);
                u = fmaf(xv[rr][4], w1.x, u);
                u = fmaf(xv[rr][5], w1.y, u);
                u = fmaf(xv[rr][6], w1.z, u);
                u = fmaf(xv[rr][7], w1.w, u);
                a = fmaf(u, v[o], a);
            }
            #pragma unroll
            for (int off = 32; off > 0; off >>= 1)
                a += __shfl_down(a, off, 64);
            if (lane == 0) red[wv][rr * C_ + c] = a;
        }
    }

    __syncthreads();
    if (tid < 2 * C_) {
        const float t = red[0][tid] + red[1][tid] + red[2][tid] + red[3][tid];
        const int rr = tid / C_;
        const int c  = tid % C_;
        amean[(size_t)(r0 + rr) * C_ + c] = t * (1.0f / (float)B_);
    }
}

__global__ __launch_bounds__(256) void k_soft(const float* __restrict__ amean,
                                              float* __restrict__ bij,
                                              float* __restrict__ cij) {
    const int c   = blockIdx.x;
    const int tid = threadIdx.x;
    __shared__ float sred[4];

    float vals[5];
    float m = -1e30f;
    #pragma unroll
    for (int k = 0; k < 5; ++k) {
        const int r = tid + 256 * k;
        if (r < R_) {
            const size_t idx = (size_t)r * C_ + c;
            const float vv = bij[idx] + amean[idx];
            bij[idx] = vv;
            vals[k] = vv;
            m = fmaxf(m, vv);
        } else {
            vals[k] = -1e30f;
        }
    }
    #pragma unroll
    for (int off = 32; off > 0; off >>= 1)
        m = fmaxf(m, __shfl_down(m, off, 64));
    if ((tid & 63) == 0) sred[tid >> 6] = m;
    __syncthreads();
    const float bm = fmaxf(fmaxf(sred[0], sred[1]), fmaxf(sred[2], sred[3]));
    __syncthreads();

    float se = 0.f;
    #pragma unroll
    for (int k = 0; k < 5; ++k)
        se += (vals[k] > -1e29f) ? expf(vals[k] - bm) : 0.f;
    #pragma unroll
    for (int off = 32; off > 0; off >>= 1)
        se += __shfl_down(se, off, 64);
    if ((tid & 63) == 0) sred[tid >> 6] = se;
    __syncthreads();
    const float inv = 1.0f / (sred[0] + sred[1] + sred[2] + sred[3]);

    #pragma unroll
    for (int k = 0; k < 5; ++k) {
        const int r = tid + 256 * k;
        if (r < R_) cij[(size_t)r * C_ + c] = expf(vals[k] - bm) * inv;
    }
}

__global__ __launch_bounds__(256) void k_squash(float* __restrict__ s) {
    const int idx = blockIdx.x * 256 + threadIdx.x;
    if (idx < B_ * CO_) s[idx] = squashf(s[idx]);
}

} // namespace

extern "C" void kernel_launch(void* const* d_in, const int* in_sizes, int n_in,
                              void* d_out, int out_size, void* d_ws, size_t ws_size,
                              hipStream_t stream) {
    const float* x  = (const float*)d_in[0];   // [256,1152,8]
    const float* Wm = (const float*)d_in[1];   // [1152,10,16,8]
    float* out = (float*)d_out;                // [256,10,16] flat = 40960
    float* ws  = (float*)d_ws;

    const size_t need = FL_TOTAL * sizeof(float);

    if (ws_size >= need) {
        float* xT    = ws + XT_OFF;
        float* spart = ws + SP_OFF;
        float* v     = ws + V_OFF;
        float* bijT  = ws + BIJ_OFF;

        // --- preferred: single cooperative launch ---
        static int coop = -1;
        if (coop < 0) {
            int dev = 0;
            (void)hipGetDevice(&dev);
            int val = 0;
            if (hipDeviceGetAttribute(&val, hipDeviceAttributeCooperativeLaunch,
                                      dev) != hipSuccess)
                val = 0;
            coop = val;
        }
        bool done = false;
        if (coop) {
            void* args[] = {(void*)&x, (void*)&Wm, (void*)&out,
                            (void*)&xT, (void*)&spart, (void*)&v, (void*)&bijT};
            if (hipLaunchCooperativeKernel((void*)k_fused, dim3(GRID_), dim3(256),
                                           args, 0, stream) == hipSuccess)
                done = true;
        }

        if (!done) {
            // --- fallback: 9 plain launches, same bodies ---
            k_trw<<<NVB_T_, 256, 0, stream>>>(x, xT, bijT);

            k_s5w<<<NVB_S_, 256, 0, stream>>>(xT, Wm, bijT, spart, 1);
            k_v3w<<<NVB_V_, 256, 0, stream>>>(spart, v);
            k_a4w<<<NVB_A_, 256, 0, stream>>>(xT, Wm, v, bijT);

            k_s5w<<<NVB_S_, 256, 0, stream>>>(xT, Wm, bijT, spart, 0);
            k_v3w<<<NVB_V_, 256, 0, stream>>>(spart, v);
            k_a4w<<<NVB_A_, 256, 0, stream>>>(xT, Wm, v, bijT);

            k_s5w<<<NVB_S_, 256, 0, stream>>>(xT, Wm, bijT, spart, 0);
            k_v3w<<<NVB_V_, 256, 0, stream>>>(spart, out);
        }
    } else {
        // ---------------- tier 3 ----------------
        float* s_buf = ws;
        float* cij   = ws + 40960;
        float* bij   = cij + R_ * C_;
        float* amean = bij + R_ * C_;

        const dim3 gsf(KSF_, C_, B_ / MBF_);

        hipMemsetAsync(bij, 0, R_ * C_ * sizeof(float), stream);

        hipMemsetAsync(s_buf, 0, B_ * CO_ * sizeof(float), stream);
        k_s_f<true><<<gsf, 256, 0, stream>>>(x, Wm, cij, s_buf);
        k_a_f<<<R_ / 2, 256, 0, stream>>>(x, Wm, s_buf, amean);
        k_soft<<<C_, 256, 0, stream>>>(amean, bij, cij);

        hipMemsetAsync(s_buf, 0, B_ * CO_ * sizeof(float), stream);
        k_s_f<false><<<gsf, 256, 0, stream>>>(x, Wm, cij, s_buf);
        k_a_f<<<R_ / 2, 256, 0, stream>>>(x, Wm, s_buf, amean);
        k_soft<<<C_, 256, 0, stream>>>(amean, bij, cij);

        hipMemsetAsync(out, 0, B_ * CO_ * sizeof(float), stream);
        k_s_f<false><<<gsf, 256, 0, stream>>>(x, Wm, cij, out);
        k_squash<<<(B_ * CO_ + 255) / 256, 256, 0, stream>>>(out);
    }
}

// Round 3
// 220.249 us; speedup vs baseline: 2.9093x; 2.9093x over previous
//
#include <hip/hip_runtime.h>
#include <math.h>

namespace {

constexpr int B_ = 256;
constexpr int R_ = 1152;
constexpr int C_ = 10;
constexpr int O_ = 16;
constexpr int I_ = 8;
constexpr int CO_ = C_ * O_;          // 160
constexpr int WRI_ = C_ * O_ * I_;    // 1280 floats of W per route

constexpr int KS_  = 64;              // r-splits in s-phase
constexpr int RC_  = R_ / KS_;        // 18 routes per s-block
constexpr int RT_  = 2;               // routes per a-block -> 576 blocks
constexpr int VSEG_ = 8;              // b-segments in v-phase -> 1280 blocks

// fallback tier-3 params
constexpr int KSF_ = 16;
constexpr int RCF_ = R_ / KSF_;       // 72
constexpr int MBF_ = 16;

// ws layout (float offsets)
constexpr size_t XT_OFF    = 0;                          // [R][B][I]
constexpr size_t XT_N      = (size_t)R_ * B_ * I_;       // 2,359,296
constexpr size_t SP_OFF    = XT_OFF + XT_N;              // [CO][KS][B]
constexpr size_t SP_N      = (size_t)CO_ * KS_ * B_;     // 2,621,440
constexpr size_t V_OFF     = SP_OFF + SP_N;              // [B][CO]
constexpr size_t V_N       = (size_t)B_ * CO_;           // 40,960
constexpr size_t BIJ_OFF   = V_OFF + V_N;                // [C][R]
constexpr size_t BIJ_N     = (size_t)C_ * R_;            // 11,520
constexpr size_t CIJ_OFF   = BIJ_OFF + BIJ_N;            // [C][R]
constexpr size_t CIJ_N     = (size_t)C_ * R_;
constexpr size_t FL_TOTAL  = CIJ_OFF + CIJ_N;

__device__ __forceinline__ float squashf(float s) {
    // faithful to reference: s^2*s/((1+s^2)*sqrt(s^2)) == s*|s|/(1+s^2)
    return s * fabsf(s) / (1.0f + s * s);
}

// ===========================================================================
// k_tr2: x[b,r,i] -> xT[r,b,i] (+ zero bijT).  tile 8 b x 32 r.  grid 1152.
// ===========================================================================
__global__ __launch_bounds__(256) void k_tr2(const float* __restrict__ x,
                                             float* __restrict__ xT,
                                             float* __restrict__ bijT) {
    __shared__ float t[8][32][8];
    const int tid = threadIdx.x;
    {
        const int gi = blockIdx.x * 256 + tid;
        if (gi < C_ * R_) bijT[gi] = 0.f;
    }
    const int r0 = (blockIdx.x % 36) * 32;
    const int b0 = (blockIdx.x / 36) * 8;
    {
        const int rl = tid & 31, bl = tid >> 5;
        const float4* p = (const float4*)(x + ((size_t)(b0 + bl) * R_ + (r0 + rl)) * I_);
        const float4 a0 = p[0], a1 = p[1];
        float* d = &t[bl][rl][0];
        *(float4*)d = a0;
        *(float4*)(d + 4) = a1;
    }
    __syncthreads();
    {
        const int f = tid & 7, rw = tid >> 3;   // f = b-local
        const float* s8 = &t[f][rw][0];
        const float4 a0 = *(const float4*)s8, a1 = *(const float4*)(s8 + 4);
        float* d = xT + ((size_t)(r0 + rw) * B_ + (b0 + f)) * I_;
        *(float4*)d = a0;
        *(float4*)(d + 4) = a1;
    }
}

// ===========================================================================
// k_cw: cijT[c,r] = softmax_r(bijT[c,:]).  grid C_=10, 256 thr.
// ===========================================================================
__global__ __launch_bounds__(256) void k_cw(const float* __restrict__ bijT,
                                            float* __restrict__ cijT) {
    __shared__ float sred[8];
    const int c    = blockIdx.x;
    const int tid  = threadIdx.x;
    const int lane = tid & 63;
    const float* bc = bijT + (size_t)c * R_;

    float bv[5];
    float m = -1e30f;
    #pragma unroll
    for (int k = 0; k < 5; ++k) {
        const int r = tid + 256 * k;
        bv[k] = (r < R_) ? bc[r] : -1e30f;
        m = fmaxf(m, bv[k]);
    }
    #pragma unroll
    for (int off = 32; off > 0; off >>= 1)
        m = fmaxf(m, __shfl_down(m, off, 64));
    if (lane == 0) sred[tid >> 6] = m;
    __syncthreads();
    const float bm = fmaxf(fmaxf(sred[0], sred[1]), fmaxf(sred[2], sred[3]));
    float se = 0.f;
    #pragma unroll
    for (int k = 0; k < 5; ++k)
        se += (bv[k] > -1e29f) ? expf(bv[k] - bm) : 0.f;
    #pragma unroll
    for (int off = 32; off > 0; off >>= 1)
        se += __shfl_down(se, off, 64);
    if (lane == 0) sred[4 + (tid >> 6)] = se;
    __syncthreads();
    const float inv = 1.0f / (sred[4] + sred[5] + sred[6] + sred[7]);
    #pragma unroll
    for (int k = 0; k < 5; ++k) {
        const int r = tid + 256 * k;
        if (r < R_) cijT[(size_t)c * R_ + r] = expf(bv[k] - bm) * inv;
    }
}

// ===========================================================================
// k_s6: spart[c*O+o, ks, b] = sum_{r in chunk} cw[r,c]*dot(W[r,c,o,:], xT[r,b,:])
// grid (C_, KS_, 4) = 2560 blocks -> 8 blocks/CU (wave-capped) = ~full occupancy.
// 256 thr = 4 o-waves x 64 b (lane).  W chunk (18 r x 128) staged in LDS with
// cw folded in; x read straight from global (L1 serves the 4-wave reuse).
// Inner loop per r per thread: 2 global f4 + 8 broadcast-LDS f4 + 32 fma.
// ===========================================================================
template <bool UNIFORM>
__global__ __launch_bounds__(256) void k_s6(const float* __restrict__ xT,
                                            const float* __restrict__ Wm,
                                            const float* __restrict__ cijT,
                                            float* __restrict__ spart) {
    __shared__ __align__(16) float wl[RC_ * 128];   // 9.2 KB
    __shared__ float cwch[RC_];

    const int tid  = threadIdx.x;
    const int lane = tid & 63;
    const int c    = blockIdx.x;          // 0..9
    const int ks   = blockIdx.y;          // 0..63
    const int bq   = blockIdx.z;          // 0..3
    const int r0   = ks * RC_;

    if (!UNIFORM) {
        if (tid < RC_) cwch[tid] = cijT[(size_t)c * R_ + r0 + tid];
        __syncthreads();
    }

    // stage cw-scaled W chunk: 18 r x 32 f4 = 576 f4
    {
        const float4* src = (const float4*)(Wm + ((size_t)r0 * C_ + c) * 128);
        float4* dst = (float4*)wl;
        #pragma unroll
        for (int k = 0; k < 3; ++k) {
            const int idx = tid + 256 * k;
            if (idx < RC_ * 32) {
                const int r = idx >> 5, q = idx & 31;
                float4 wv = src[(size_t)r * (C_ * 32) + q];
                const float cw = UNIFORM ? (1.0f / (float)R_) : cwch[r];
                wv.x *= cw; wv.y *= cw; wv.z *= cw; wv.w *= cw;
                dst[idx] = wv;
            }
        }
    }
    __syncthreads();

    const int o0 = (tid >> 6) * 4;        // wave-uniform -> LDS broadcast reads
    const float* xbase = xT + ((size_t)r0 * B_ + bq * 64 + lane) * I_;

    float acc[4] = {0.f, 0.f, 0.f, 0.f};

    #pragma unroll 3
    for (int r = 0; r < RC_; ++r) {
        const float4* xp = (const float4*)(xbase + (size_t)r * B_ * I_);
        const float4 a0 = xp[0], a1 = xp[1];
        const float4* wp = (const float4*)&wl[r * 128 + o0 * 8];
        #pragma unroll
        for (int oo = 0; oo < 4; ++oo) {
            const float4 w0 = wp[oo * 2 + 0];
            const float4 w1 = wp[oo * 2 + 1];
            float a = acc[oo];
            a = fmaf(a0.x, w0.x, a);
            a = fmaf(a0.y, w0.y, a);
            a = fmaf(a0.z, w0.z, a);
            a = fmaf(a0.w, w0.w, a);
            a = fmaf(a1.x, w1.x, a);
            a = fmaf(a1.y, w1.y, a);
            a = fmaf(a1.z, w1.z, a);
            a = fmaf(a1.w, w1.w, a);
            acc[oo] = a;
        }
    }

    float* sp = spart + (((size_t)(c * O_ + o0)) * KS_ + ks) * B_ + bq * 64 + lane;
    #pragma unroll
    for (int oo = 0; oo < 4; ++oo)
        sp[(size_t)oo * KS_ * B_] = acc[oo];
}

// ===========================================================================
// k_v4: dest[b,co] = squash(sum_ks spart[co,ks,b]).  grid 1280 (co x 8 bsegs
// of 32 b), 256 thr = 8 ks-groups x 32 b; each thread sums 8 partials.
// ===========================================================================
__global__ __launch_bounds__(256) void k_v4(const float* __restrict__ spart,
                                            float* __restrict__ dest) {
    __shared__ float sh[7 * 32];
    const int tid  = threadIdx.x;
    const int bl   = tid & 31;
    const int g    = tid >> 5;            // 0..7
    const int co2  = blockIdx.x % CO_;
    const int bseg = blockIdx.x / CO_;    // 0..7
    const float* p = spart + (((size_t)co2) * KS_ + g * 8) * B_ + bseg * 32 + bl;
    float t0 = 0.f, t1 = 0.f;
    #pragma unroll
    for (int j = 0; j < 8; j += 2) {
        t0 += p[(size_t)(j + 0) * B_];
        t1 += p[(size_t)(j + 1) * B_];
    }
    const float s = t0 + t1;
    if (g) sh[(g - 1) * 32 + bl] = s;
    __syncthreads();
    if (g == 0) {
        float tot = s;
        #pragma unroll
        for (int k = 0; k < 7; ++k) tot += sh[k * 32 + bl];
        const int b = bseg * 32 + bl;
        dest[(size_t)b * CO_ + co2] = squashf(tot);
    }
}

// ===========================================================================
// k_a5: bijT[c, r0+rr] += (1/B) sum_o sum_i W[r,c,o,i]*(sum_b v[b,c,o]*xT[r,b,i])
// grid R_/RT_ = 576 blocks, 640 thr = 160 co x 4 b-groups of 64.
// ===========================================================================
__global__ __launch_bounds__(640) void k_a5(const float* __restrict__ xT,
                                            const float* __restrict__ Wm,
                                            const float* __restrict__ v,
                                            float* __restrict__ bijT) {
    __shared__ __align__(16) float xrow[RT_ * B_ * I_];   // 16 KB
    __shared__ float part[RT_][640];

    const int tid = threadIdx.x;
    const int r0  = blockIdx.x * RT_;

    for (int k = tid; k < RT_ * B_ * I_ / 4; k += 640)
        ((float4*)xrow)[k] = ((const float4*)(xT + (size_t)r0 * B_ * I_))[k];
    __syncthreads();

    const int co = tid % CO_;
    const int bg = tid / CO_;
    const int b0 = bg * 64;

    float acc[RT_][8];
    #pragma unroll
    for (int rr = 0; rr < RT_; ++rr)
        #pragma unroll
        for (int i = 0; i < 8; ++i) acc[rr][i] = 0.f;

    const float* vp = v + co;
    #pragma unroll 2
    for (int bb = 0; bb < 64; ++bb) {
        const int b = b0 + bb;
        const float vt = vp[(size_t)b * CO_];
        #pragma unroll
        for (int rr = 0; rr < RT_; ++rr) {
            const float4 y0 = *(const float4*)(&xrow[(rr * B_ + b) * I_]);
            const float4 y1 = *(const float4*)(&xrow[(rr * B_ + b) * I_ + 4]);
            acc[rr][0] = fmaf(vt, y0.x, acc[rr][0]);
            acc[rr][1] = fmaf(vt, y0.y, acc[rr][1]);
            acc[rr][2] = fmaf(vt, y0.z, acc[rr][2]);
            acc[rr][3] = fmaf(vt, y0.w, acc[rr][3]);
            acc[rr][4] = fmaf(vt, y1.x, acc[rr][4]);
            acc[rr][5] = fmaf(vt, y1.y, acc[rr][5]);
            acc[rr][6] = fmaf(vt, y1.z, acc[rr][6]);
            acc[rr][7] = fmaf(vt, y1.w, acc[rr][7]);
        }
    }

    #pragma unroll
    for (int rr = 0; rr < RT_; ++rr) {
        const float* wp = Wm + (((size_t)(r0 + rr)) * CO_ + co) * I_;
        const float4 w0 = *(const float4*)wp;
        const float4 w1 = *(const float4*)(wp + 4);
        const float p0 = fmaf(acc[rr][1], w0.y, acc[rr][0] * w0.x);
        const float p1 = fmaf(acc[rr][3], w0.w, acc[rr][2] * w0.z);
        const float p2 = fmaf(acc[rr][5], w1.y, acc[rr][4] * w1.x);
        const float p3 = fmaf(acc[rr][7], w1.w, acc[rr][6] * w1.z);
        part[rr][tid] = (p0 + p1) + (p2 + p3);
    }
    __syncthreads();

    if (tid < CO_) {
        #pragma unroll
        for (int rr = 0; rr < RT_; ++rr) {
            float a = part[rr][tid] + part[rr][CO_ + tid] +
                      part[rr][2 * CO_ + tid] + part[rr][3 * CO_ + tid];
            #pragma unroll
            for (int off = 8; off > 0; off >>= 1)
                a += __shfl_down(a, off, 16);
            if ((tid & 15) == 0)
                bijT[(size_t)(tid >> 4) * R_ + (r0 + rr)] += a * (1.0f / (float)B_);
        }
    }
}

// ===========================================================================
// FALLBACK tier 3 (tiny ws)
// ===========================================================================
template <bool UNIFORM>
__global__ __launch_bounds__(256) void k_s_f(const float* __restrict__ x,
                                             const float* __restrict__ Wm,
                                             const float* __restrict__ cij,
                                             float* __restrict__ s_out) {
    const int o  = threadIdx.x & 15;
    const int tb = threadIdx.x >> 4;
    const int b  = blockIdx.z * MBF_ + tb;
    const int c  = blockIdx.y;
    const int r0 = blockIdx.x * RCF_;

    const float* xp = x + ((size_t)b * R_ + r0) * I_;
    const float* wp = Wm + (((size_t)r0 * C_ + c) * O_ + o) * I_;
    const float* cp = cij + (size_t)r0 * C_ + c;

    float acc = 0.f;
    #pragma unroll 4
    for (int r = 0; r < RCF_; ++r) {
        const float4 xv0 = *(const float4*)(xp);
        const float4 xv1 = *(const float4*)(xp + 4);
        const float4 wv0 = *(const float4*)(wp);
        const float4 wv1 = *(const float4*)(wp + 4);
        const float p0 = fmaf(xv0.y, wv0.y, xv0.x * wv0.x);
        const float p1 = fmaf(xv0.w, wv0.w, xv0.z * wv0.z);
        const float p2 = fmaf(xv1.y, wv1.y, xv1.x * wv1.x);
        const float p3 = fmaf(xv1.w, wv1.w, xv1.z * wv1.z);
        const float cw = UNIFORM ? (1.0f / (float)R_) : cp[0];
        acc = fmaf(cw, (p0 + p1) + (p2 + p3), acc);
        xp += I_;
        wp += WRI_;
        cp += C_;
    }
    atomicAdd(&s_out[((size_t)b * C_ + c) * O_ + o], acc);
}

__global__ __launch_bounds__(256) void k_a_f(const float* __restrict__ x,
                                             const float* __restrict__ Wm,
                                             const float* __restrict__ s_in,
                                             float* __restrict__ amean) {
    __shared__ __align__(16) float wlds[2 * WRI_];
    __shared__ float red[4][2 * C_];

    const int tid = threadIdx.x;
    const int r0  = blockIdx.x * 2;

    const float* wsrc = Wm + (size_t)r0 * WRI_;
    #pragma unroll
    for (int k = 0; k < 2 * WRI_ / 256; ++k)
        wlds[tid + 256 * k] = wsrc[tid + 256 * k];
    __syncthreads();

    const int b    = tid;
    const int lane = tid & 63;
    const int wv   = tid >> 6;

    float xv[2][I_];
    const float4* xp4 = (const float4*)(x + ((size_t)b * R_ + r0) * I_);
    #pragma unroll
    for (int rr = 0; rr < 2; ++rr) {
        const float4 a0 = xp4[rr * 2 + 0];
        const float4 a1 = xp4[rr * 2 + 1];
        xv[rr][0] = a0.x; xv[rr][1] = a0.y; xv[rr][2] = a0.z; xv[rr][3] = a0.w;
        xv[rr][4] = a1.x; xv[rr][5] = a1.y; xv[rr][6] = a1.z; xv[rr][7] = a1.w;
    }

    #pragma unroll 1
    for (int c = 0; c < C_; ++c) {
        const float4* sp4 = (const float4*)(s_in + ((size_t)b * C_ + c) * O_);
        float v[O_];
        #pragma unroll
        for (int q = 0; q < 4; ++q) {
            const float4 sv = sp4[q];
            v[q * 4 + 0] = squashf(sv.x);
            v[q * 4 + 1] = squashf(sv.y);
            v[q * 4 + 2] = squashf(sv.z);
            v[q * 4 + 3] = squashf(sv.w);
        }
        #pragma unroll 1
        for (int rr = 0; rr < 2; ++rr) {
            const float4* wl4 = (const float4*)&wlds[(rr * C_ + c) * O_ * I_];
            float a = 0.f;
            #pragma unroll
            for (int o = 0; o < O_; ++o) {
                const float4 w0 = wl4[o * 2 + 0];
                const float4 w1 = wl4[o * 2 + 1];
                float u = xv[rr][0] * w0.x;
                u = fmaf(xv[rr][1], w0.y, u);
                u = fmaf(xv[rr][2], w0.z, u);
                u = fmaf(xv[rr][3], w0.w, u);
                u = fmaf(xv[rr][4], w1.x, u);
                u = fmaf(xv[rr][5], w1.y, u);
                u = fmaf(xv[rr][6], w1.z, u);
                u = fmaf(xv[rr][7], w1.w, u);
                a = fmaf(u, v[o], a);
            }
            #pragma unroll
            for (int off = 32; off > 0; off >>= 1)
                a += __shfl_down(a, off, 64);
            if (lane == 0) red[wv][rr * C_ + c] = a;
        }
    }

    __syncthreads();
    if (tid < 2 * C_) {
        const float t = red[0][tid] + red[1][tid] + red[2][tid] + red[3][tid];
        const int rr = tid / C_;
        const int c  = tid % C_;
        amean[(size_t)(r0 + rr) * C_ + c] = t * (1.0f / (float)B_);
    }
}

__global__ __launch_bounds__(256) void k_soft(const float* __restrict__ amean,
                                              float* __restrict__ bij,
                                              float* __restrict__ cij) {
    const int c   = blockIdx.x;
    const int tid = threadIdx.x;
    __shared__ float sred[4];

    float vals[5];
    float m = -1e30f;
    #pragma unroll
    for (int k = 0; k < 5; ++k) {
        const int r = tid + 256 * k;
        if (r < R_) {
            const size_t idx = (size_t)r * C_ + c;
            const float vv = bij[idx] + amean[idx];
            bij[idx] = vv;
            vals[k] = vv;
            m = fmaxf(m, vv);
        } else {
            vals[k] = -1e30f;
        }
    }
    #pragma unroll
    for (int off = 32; off > 0; off >>= 1)
        m = fmaxf(m, __shfl_down(m, off, 64));
    if ((tid & 63) == 0) sred[tid >> 6] = m;
    __syncthreads();
    const float bm = fmaxf(fmaxf(sred[0], sred[1]), fmaxf(sred[2], sred[3]));
    __syncthreads();

    float se = 0.f;
    #pragma unroll
    for (int k = 0; k < 5; ++k)
        se += (vals[k] > -1e29f) ? expf(vals[k] - bm) : 0.f;
    #pragma unroll
    for (int off = 32; off > 0; off >>= 1)
        se += __shfl_down(se, off, 64);
    if ((tid & 63) == 0) sred[tid >> 6] = se;
    __syncthreads();
    const float inv = 1.0f / (sred[0] + sred[1] + sred[2] + sred[3]);

    #pragma unroll
    for (int k = 0; k < 5; ++k) {
        const int r = tid + 256 * k;
        if (r < R_) cij[(size_t)r * C_ + c] = expf(vals[k] - bm) * inv;
    }
}

__global__ __launch_bounds__(256) void k_squash(float* __restrict__ s) {
    const int idx = blockIdx.x * 256 + threadIdx.x;
    if (idx < B_ * CO_) s[idx] = squashf(s[idx]);
}

} // namespace

extern "C" void kernel_launch(void* const* d_in, const int* in_sizes, int n_in,
                              void* d_out, int out_size, void* d_ws, size_t ws_size,
                              hipStream_t stream) {
    const float* x  = (const float*)d_in[0];   // [256,1152,8]
    const float* Wm = (const float*)d_in[1];   // [1152,10,16,8]
    float* out = (float*)d_out;                // [256,10,16] flat = 40960
    float* ws  = (float*)d_ws;

    const size_t need = FL_TOTAL * sizeof(float);

    if (ws_size >= need) {
        // ---------------- main path: 11 nodes ----------------
        float* xT    = ws + XT_OFF;
        float* spart = ws + SP_OFF;
        float* v     = ws + V_OFF;
        float* bijT  = ws + BIJ_OFF;
        float* cijT  = ws + CIJ_OFF;

        const dim3 gs(C_, KS_, 4);                // 2560 blocks

        k_tr2<<<1152, 256, 0, stream>>>(x, xT, bijT);

        // iter 0 (uniform weights; softmax(0) == 1/R)
        k_s6<true><<<gs, 256, 0, stream>>>(xT, Wm, cijT, spart);
        k_v4<<<CO_ * VSEG_, 256, 0, stream>>>(spart, v);
        k_a5<<<R_ / RT_, 640, 0, stream>>>(xT, Wm, v, bijT);

        // iter 1
        k_cw<<<C_, 256, 0, stream>>>(bijT, cijT);
        k_s6<false><<<gs, 256, 0, stream>>>(xT, Wm, cijT, spart);
        k_v4<<<CO_ * VSEG_, 256, 0, stream>>>(spart, v);
        k_a5<<<R_ / RT_, 640, 0, stream>>>(xT, Wm, v, bijT);

        // iter 2: final v straight into d_out
        k_cw<<<C_, 256, 0, stream>>>(bijT, cijT);
        k_s6<false><<<gs, 256, 0, stream>>>(xT, Wm, cijT, spart);
        k_v4<<<CO_ * VSEG_, 256, 0, stream>>>(spart, out);
    } else {
        // ---------------- tier 3 ----------------
        float* s_buf = ws;
        float* cij   = ws + 40960;
        float* bij   = cij + R_ * C_;
        float* amean = bij + R_ * C_;

        const dim3 gsf(KSF_, C_, B_ / MBF_);

        hipMemsetAsync(bij, 0, R_ * C_ * sizeof(float), stream);

        hipMemsetAsync(s_buf, 0, B_ * CO_ * sizeof(float), stream);
        k_s_f<true><<<gsf, 256, 0, stream>>>(x, Wm, cij, s_buf);
        k_a_f<<<R_ / 2, 256, 0, stream>>>(x, Wm, s_buf, amean);
        k_soft<<<C_, 256, 0, stream>>>(amean, bij, cij);

        hipMemsetAsync(s_buf, 0, B_ * CO_ * sizeof(float), stream);
        k_s_f<false><<<gsf, 256, 0, stream>>>(x, Wm, cij, s_buf);
        k_a_f<<<R_ / 2, 256, 0, stream>>>(x, Wm, s_buf, amean);
        k_soft<<<C_, 256, 0, stream>>>(amean, bij, cij);

        hipMemsetAsync(out, 0, B_ * CO_ * sizeof(float), stream);
        k_s_f<false><<<gsf, 256, 0, stream>>>(x, Wm, cij, out);
        k_squash<<<(B_ * CO_ + 255) / 256, 256, 0, stream>>>(out);
    }
}